// Round 4
// baseline (95.368 us; speedup 1.0000x reference)
//
#include <hip/hip_runtime.h>

// CondConv2d B=16,CIN=COUT=128,H=W=56,E=4,3x3,pad=1 fp32.
// Pipeline: (1) fold routing into bf16 weights Wmix[b][cc][tap][co][ci_l];
//           (2) cast x -> padded bf16 xbf[b][row][col][ci] (halo zeroed);
//           (3) barrier-free, LDS-free MFMA conv: every fragment is a direct
//               global load (L1/L2-resident), depth-2 software pipeline.

typedef float  f32x4 __attribute__((ext_vector_type(4)));
typedef short  s16x8 __attribute__((ext_vector_type(8)));

#define CIN   128
#define COUT  128
#define HH    56
#define WW    56
#define SP    (HH*WW)          // 3136
#define EW    147456           // per-expert W elems
#define BW_   147456           // per-sample Wmix elems: [cc4][tap9][co128][ci32]
#define XCOLS 66               // cols -1..64 (w padded to 64 + halo)
#define XROWS 58               // rows -1..56
#define XRST  (XCOLS*CIN)      // 8448 elems per row
#define XBSZ  (XROWS*XRST)     // 489984 elems per sample

static __device__ __forceinline__ unsigned short f2bf(float f) {
    unsigned u = __builtin_bit_cast(unsigned, f);
    return (unsigned short)((u + 0x7FFFu + ((u >> 16) & 1u)) >> 16);
}

// ---------------------------------------------------------------------------
// Phase 1: Wmix[b][cc][tap][co][ci_l] (bf16) = sum_e r[b,e]*W[e][co][cc*32+ci_l][tap]
// Each thread reads its 4 expert weights ONCE, writes all 16 samples.
// ---------------------------------------------------------------------------
__global__ __launch_bounds__(256) void mix_kernel(const float* __restrict__ W,
                                                  const float* __restrict__ r,
                                                  unsigned short* __restrict__ Wmix) {
    int o = blockIdx.x * 256 + threadIdx.x;      // [0, 147456)
    int ci_l = o & 31;
    int o2   = o >> 5;
    int co   = o2 & 127;
    int o3   = o2 >> 7;                          // [0,36)
    int tap  = o3 % 9;
    int cc   = o3 / 9;
    int ci   = cc * 32 + ci_l;
    size_t src = ((size_t)co * CIN + ci) * 9 + tap;
    float w0 = W[src], w1 = W[src + EW], w2 = W[src + 2*EW], w3 = W[src + 3*EW];
    #pragma unroll
    for (int b = 0; b < 16; ++b) {
        float acc = r[b*4+0]*w0 + r[b*4+1]*w1 + r[b*4+2]*w2 + r[b*4+3]*w3;
        Wmix[(size_t)b * BW_ + o] = f2bf(acc);
    }
}

// ---------------------------------------------------------------------------
// Phase 2: xbf[b][row][col][ci] bf16, rows/cols include zeroed halo+right pad.
// LDS transpose so global read (w-fastest) AND write (ci-fastest) coalesce.
// ---------------------------------------------------------------------------
__global__ __launch_bounds__(256) void xcast_kernel(const float* __restrict__ x,
                                                    unsigned short* __restrict__ xbf) {
    __shared__ unsigned short tile[CIN * XCOLS];  // 16.9 KB
    const int row = blockIdx.x;                   // 0..57
    const int b   = blockIdx.y;
    const int t   = threadIdx.x;
    const int hin = row - 1;
    const float* xb = x + (size_t)b * CIN * SP;
    for (int s = t; s < CIN * XCOLS; s += 256) {
        int col = s % XCOLS;
        int ci  = s / XCOLS;
        int w   = col - 1;
        unsigned short v = 0;
        if ((unsigned)hin < 56u && (unsigned)w < 56u)
            v = f2bf(xb[(size_t)ci * SP + hin*56 + w]);
        tile[ci * XCOLS + col] = v;
    }
    __syncthreads();
    unsigned short* dst = xbf + (size_t)b * XBSZ + (size_t)row * XRST;
    for (int s = t; s < XCOLS * 16; s += 256) {
        int oc  = s & 15;
        int col = s >> 4;
        s16x8 v;
        #pragma unroll
        for (int j = 0; j < 8; ++j) v[j] = (short)tile[(oc*8 + j) * XCOLS + col];
        *(s16x8*)&dst[col * CIN + oc*8] = v;
    }
}

// ---------------------------------------------------------------------------
// Phase 3: barrier-free MFMA conv. Block = (b,h); 4 waves = 2(co-half)x2(w-half).
// Wave: 64co x 32px, K=1152 -> 36 ksteps x {4 A-loads, 2 B-loads, 8 MFMAs}.
// A: linear walk through Wmix (permuted-contiguous 1KB/frag).
// B: direct 16B/lane gather from padded xbf (16 fully-used 64B lines/frag).
// Depth-2 pipeline, 3 fragment buffers, fully unrolled (static reg indices).
// ---------------------------------------------------------------------------
__global__ __launch_bounds__(256, 4) void conv_mfma(const unsigned short* __restrict__ xbf,
                                                    const unsigned short* __restrict__ Wmix,
                                                    float* __restrict__ out) {
    const int bid = blockIdx.x;
    const int bs  = (bid & 7) * 112 + (bid >> 3);   // bijective XCD swizzle (896=8*112)
    const int b   = bs / 56;
    const int h   = bs % 56;
    const int t    = threadIdx.x;
    const int lane = t & 63;
    const int l15  = lane & 15;
    const int kg   = lane >> 4;
    const int wt   = (t >> 6) & 1;                  // w half (px base wt*32)
    const int wm   = t >> 7;                        // co half

    const unsigned short* ab = Wmix + (size_t)b*BW_ + (wm*64 + l15)*32 + kg*8;
    const unsigned short* xb = xbf  + (size_t)b*XBSZ + (size_t)h*XRST
                               + (wt*32 + l15)*CIN + kg*8;

    f32x4 acc[4][2];
    #pragma unroll
    for (int mf = 0; mf < 4; ++mf)
        #pragma unroll
        for (int nf = 0; nf < 2; ++nf) acc[mf][nf] = (f32x4)0.f;

    s16x8 a[3][4];
    s16x8 bv[3][2];

#define LOADSTEP(S, BUF) {                                        \
    const unsigned short* ap_ = ab + (S)*4096;                    \
    a[BUF][0] = *(const s16x8*)(ap_);                             \
    a[BUF][1] = *(const s16x8*)(ap_ + 512);                       \
    a[BUF][2] = *(const s16x8*)(ap_ + 1024);                      \
    a[BUF][3] = *(const s16x8*)(ap_ + 1536);                      \
    const unsigned short* bp_ = xb + (((S)%9)/3)*XRST             \
                                   + ((S)%3)*CIN + ((S)/9)*32;    \
    bv[BUF][0] = *(const s16x8*)(bp_);                            \
    bv[BUF][1] = *(const s16x8*)(bp_ + 16*CIN); }

    LOADSTEP(0, 0)
    LOADSTEP(1, 1)

    #pragma unroll
    for (int s = 0; s < 36; ++s) {
        if (s + 2 < 36) {
            LOADSTEP(s + 2, (s + 2) % 3)
        }
        #pragma unroll
        for (int mf = 0; mf < 4; ++mf)
            #pragma unroll
            for (int nf = 0; nf < 2; ++nf)
                acc[mf][nf] = __builtin_amdgcn_mfma_f32_16x16x32_bf16(
                    a[s % 3][mf], bv[s % 3][nf], acc[mf][nf], 0, 0, 0);
    }
#undef LOADSTEP

    // D layout: col(px)=lane&15, row(co)=(lane>>4)*4+reg
    #pragma unroll
    for (int nf = 0; nf < 2; ++nf) {
        int wout = wt*32 + nf*16 + l15;
        if (wout < 56) {
            #pragma unroll
            for (int mf = 0; mf < 4; ++mf)
                #pragma unroll
                for (int rg = 0; rg < 4; ++rg) {
                    int co = wm*64 + mf*16 + kg*4 + rg;
                    out[(((size_t)b*COUT + co)*HH + h)*WW + wout] = acc[mf][nf][rg];
                }
        }
    }
}

extern "C" void kernel_launch(void* const* d_in, const int* in_sizes, int n_in,
                              void* d_out, int out_size, void* d_ws, size_t ws_size,
                              hipStream_t stream) {
    const float* x = (const float*)d_in[0];          // [16,128,56,56]
    const float* r = (const float*)d_in[1];          // [16,4]
    const float* W = (const float*)d_in[2];          // [4,128,128,3,3]
    float* outp = (float*)d_out;                     // [16,128,56,56]
    unsigned short* Wmix = (unsigned short*)d_ws;            // 4.72 MB
    unsigned short* xbf  = Wmix + (size_t)16 * BW_;          // 15.68 MB

    mix_kernel <<<576,          256, 0, stream>>>(W, r, Wmix);
    xcast_kernel<<<dim3(58,16), 256, 0, stream>>>(x, xbf);
    conv_mfma  <<<896,          256, 0, stream>>>(xbf, Wmix, outp);
}

// Round 5
// 48.513 us; speedup vs baseline: 1.9658x; 1.9658x over previous
//
#include <hip/hip_runtime.h>

// CondConv2d B=16,CIN=COUT=128,H=W=56,E=4,3x3,pad=1 fp32.
// (1) prep: fold routing into bf16 Wmix[b][cc][tap][co][ci_l]  +  cast x into
//     padded bf16 xbf[b][row58][col66][ci128] (halo zeroed).
// (2) conv: per (b,h) block a 128x64xK=1152 MFMA GEMM using the 2-phase
//     global_load_lds double-buffered K-loop (compiler cannot sink DMA loads),
//     XOR-swizzled LDS (2-way banks = free), BK=64 (tap pair), 18 iters.

typedef float  f32x4 __attribute__((ext_vector_type(4)));
typedef short  s16x8 __attribute__((ext_vector_type(8)));

#define CIN   128
#define COUT  128
#define HH    56
#define WW    56
#define SP    (HH*WW)          // 3136
#define EW    147456           // per-expert W elems
#define BW_   147456           // per-sample Wmix elems: [cc4][tap9][co128][ci32]
#define XCOLS 66               // padded cols: input col = c-1 in [-1,64]
#define XROWS 58               // padded rows
#define XRST  (XCOLS*CIN)      // 8448
#define XBSZ  (XROWS*XRST)     // 489984

static __device__ __forceinline__ unsigned short f2bf(float f) {
    unsigned u = __builtin_bit_cast(unsigned, f);
    return (unsigned short)((u + 0x7FFFu + ((u >> 16) & 1u)) >> 16);
}

static __device__ __forceinline__ void gload16(const void* g, void* l) {
    __builtin_amdgcn_global_load_lds(
        (const __attribute__((address_space(1))) void*)g,
        (__attribute__((address_space(3))) void*)l, 16, 0, 0);
}

// ---------------------------------------------------------------------------
// prep: blocks [0,576) mix weights; [576,1504) cast/pad x. One launch.
// ---------------------------------------------------------------------------
__global__ __launch_bounds__(256) void prep_kernel(const float* __restrict__ W,
                                                   const float* __restrict__ r,
                                                   const float* __restrict__ x,
                                                   unsigned short* __restrict__ Wmix,
                                                   unsigned short* __restrict__ xbf) {
    __shared__ unsigned short tile[CIN * XCOLS];     // xcast branch only (16.9 KB)
    const int bid = blockIdx.x;
    const int t   = threadIdx.x;

    if (bid < 576) {
        // Wmix[b][cc][tap][co][ci_l] = sum_e r[b,e]*W[e][co][cc*32+ci_l][tap]
        int o = bid * 256 + t;                       // [0,147456)
        int ci_l = o & 31;
        int o2   = o >> 5;
        int co   = o2 & 127;
        int o3   = o2 >> 7;                          // [0,36)
        int tap  = o3 % 9;
        int cc   = o3 / 9;
        size_t src = ((size_t)co * CIN + cc*32 + ci_l) * 9 + tap;
        float w0 = W[src], w1 = W[src + EW], w2 = W[src + 2*EW], w3 = W[src + 3*EW];
        #pragma unroll
        for (int b = 0; b < 16; ++b) {
            float acc = r[b*4+0]*w0 + r[b*4+1]*w1 + r[b*4+2]*w2 + r[b*4+3]*w3;
            Wmix[(size_t)b * BW_ + o] = f2bf(acc);
        }
    } else {
        // xbf[b][row][col][ci], halo/right-pad zeroed, ci-fastest (LDS transpose)
        int bb  = bid - 576;                         // [0,928)
        int row = bb % XROWS;
        int b   = bb / XROWS;
        int hin = row - 1;
        const float* xb = x + (size_t)b * CIN * SP;
        for (int s = t; s < CIN * XCOLS; s += 256) {
            int col = s % XCOLS;
            int ci  = s / XCOLS;
            int w   = col - 1;
            unsigned short v = 0;
            if ((unsigned)hin < 56u && (unsigned)w < 56u)
                v = f2bf(xb[(size_t)ci * SP + hin*56 + w]);
            tile[ci * XCOLS + col] = v;
        }
        __syncthreads();
        unsigned short* dst = xbf + (size_t)b * XBSZ + (size_t)row * XRST;
        for (int s = t; s < XCOLS * 16; s += 256) {
            int oc  = s & 15;
            int col = s >> 4;
            s16x8 v;
            #pragma unroll
            for (int j = 0; j < 8; ++j) v[j] = (short)tile[(oc*8 + j) * XCOLS + col];
            *(s16x8*)&dst[col * CIN + oc*8] = v;
        }
    }
}

// ---------------------------------------------------------------------------
// conv: block=(b,h): C[128co][64px] += A[128][1152] * B[1152][64px].
// 4 waves = 2(co-half wm) x 2(px-half wn); wave = 64co x 32px (4mf x 2nf).
// 18 iters x BK=64 (two (cc,tap) k-slabs). Per iter: stage next {A 16KB, B 8KB}
// via global_load_lds; ds_read_b128 current (XOR-swizzled, 2-way banks); 32 MFMA.
// LDS: 2 bufs x 24KB. Swizzle: 16B-slot' = slot ^ ((row>>1)&3), both sides.
// ---------------------------------------------------------------------------
__global__ __launch_bounds__(256, 3) void conv_mfma(const unsigned short* __restrict__ xbf,
                                                    const unsigned short* __restrict__ Wmix,
                                                    float* __restrict__ out) {
    __shared__ __align__(16) unsigned short lds[24576];   // 48 KB
    char* ldsb = (char*)lds;

    const int bid = blockIdx.x;
    const int bs  = (bid & 7) * 112 + (bid >> 3);    // bijective XCD swizzle (896=8*112)
    const int b   = bs / 56;
    const int h   = bs % 56;
    const int t    = threadIdx.x;
    const int lane = t & 63;
    const int wid  = t >> 6;
    const int wm   = wid >> 1;                       // co half
    const int wn   = wid & 1;                        // px half
    const int l15  = lane & 15;
    const int kg   = lane >> 4;

    const unsigned short* WmixB = Wmix + (size_t)b * BW_;
    const unsigned short* xbB   = xbf  + (size_t)b * XBSZ;

    // staging per-thread source swizzle: row=t>>2, slot=t&3, chunk = slot^((row>>1)&3)
    const int srow = t >> 2;
    const int ssl  = (t & 3) ^ ((srow >> 1) & 3);
    const int a_off = srow * 32 + ssl * 8;           // elems into a 4096-elem A slab
    // frag-read swizzle (per-lane constant): byte slot' for ci-chunk kg
    const int swz = (kg ^ ((l15 >> 1) & 3)) * 16;
    const int a_rd = (wm * 64 + l15) * 64 + swz;     // + mf*1024 + tp*8192 (+bufo)
    const int b_rd = 16384 + (wn * 32 + l15) * 64 + swz; // + nf*1024 + tp*4096 (+bufo)

    f32x4 acc[4][2];
    #pragma unroll
    for (int mf = 0; mf < 4; ++mf)
        #pragma unroll
        for (int nf = 0; nf < 2; ++nf) acc[mf][nf] = (f32x4)0.f;

    auto stage = [&](int it) {
        const int bufo = (it & 1) * 24576;           // bytes
        #pragma unroll
        for (int tp = 0; tp < 2; ++tp) {
            const int s   = it * 2 + tp;             // k-slab 0..35
            const int cc  = s / 9;
            const int tap = s % 9;
            const int kh  = tap / 3;
            const int kw  = tap % 3;
            // A slab: 8KB = 2 DMA rounds (512 x 16B), lds dest lane-linear
            const unsigned short* ga = WmixB + s * 4096 + a_off;
            char* la = ldsb + bufo + tp * 8192 + wid * 1024;
            gload16(ga,        la);
            gload16(ga + 2048, la + 4096);           // round 1: co += 64
            // B tile: 64px x 32ci = 4KB = 1 DMA round
            const unsigned short* gb = xbB + (size_t)(h + kh) * XRST
                                       + (srow + kw) * CIN + cc * 32 + ssl * 8;
            char* lb = ldsb + bufo + 16384 + tp * 4096 + wid * 1024;
            gload16(gb, lb);
        }
    };

    auto compute = [&](int it) {
        const int bufo = (it & 1) * 24576;
        #pragma unroll
        for (int tp = 0; tp < 2; ++tp) {
            s16x8 af[4], bf[2];
            #pragma unroll
            for (int mf = 0; mf < 4; ++mf)
                af[mf] = *(const s16x8*)(ldsb + bufo + tp*8192 + a_rd + mf*1024);
            #pragma unroll
            for (int nf = 0; nf < 2; ++nf)
                bf[nf] = *(const s16x8*)(ldsb + bufo + tp*4096 + b_rd + nf*1024);
            #pragma unroll
            for (int mf = 0; mf < 4; ++mf)
                #pragma unroll
                for (int nf = 0; nf < 2; ++nf)
                    acc[mf][nf] = __builtin_amdgcn_mfma_f32_16x16x32_bf16(
                        af[mf], bf[nf], acc[mf][nf], 0, 0, 0);
        }
    };

    stage(0);
    __syncthreads();
    #pragma unroll
    for (int it = 0; it < 18; ++it) {
        if (it + 1 < 18) stage(it + 1);              // issue DMA before reads/MFMA
        compute(it);
        __syncthreads();                             // drains vmcnt+lgkm (compiler)
    }

    // store: D col(px)=l15, row(co)=kg*4+rg
    #pragma unroll
    for (int nf = 0; nf < 2; ++nf) {
        int wout = wn*32 + nf*16 + l15;
        if (wout < 56) {
            #pragma unroll
            for (int mf = 0; mf < 4; ++mf)
                #pragma unroll
                for (int rg = 0; rg < 4; ++rg) {
                    int co = wm*64 + mf*16 + kg*4 + rg;
                    out[(((size_t)b*COUT + co)*HH + h)*WW + wout] = acc[mf][nf][rg];
                }
        }
    }
}

extern "C" void kernel_launch(void* const* d_in, const int* in_sizes, int n_in,
                              void* d_out, int out_size, void* d_ws, size_t ws_size,
                              hipStream_t stream) {
    const float* x = (const float*)d_in[0];          // [16,128,56,56]
    const float* r = (const float*)d_in[1];          // [16,4]
    const float* W = (const float*)d_in[2];          // [4,128,128,3,3]
    float* outp = (float*)d_out;                     // [16,128,56,56]
    unsigned short* Wmix = (unsigned short*)d_ws;            // 4.72 MB
    unsigned short* xbf  = Wmix + (size_t)16 * BW_;          // 15.68 MB

    prep_kernel<<<1504, 256, 0, stream>>>(W, r, x, Wmix, xbf);
    conv_mfma  <<<896,  256, 0, stream>>>(xbf, Wmix, outp);
}

// Round 6
// 46.877 us; speedup vs baseline: 2.0344x; 1.0349x over previous
//
#include <hip/hip_runtime.h>

// CondConv2d B=16,CIN=COUT=128,H=W=56,E=4,3x3,pad=1 fp32.
// (1) prep: fold routing into bf16 Wmix[b][cc][tap][co][ci_l]  +  cast x into
//     padded bf16 xbf[b][row58][col66][ci128] (halo zeroed).
// (2) conv: per (b,h) block a 128x64xK=1152 MFMA GEMM, double-buffered
//     global_load_lds K-loop with COUNTED vmcnt (T4): prefetch stays in
//     flight across barriers — no vmcnt(0) drain in the main loop.

typedef float  f32x4 __attribute__((ext_vector_type(4)));
typedef short  s16x8 __attribute__((ext_vector_type(8)));

#define CIN   128
#define COUT  128
#define HH    56
#define WW    56
#define SP    (HH*WW)          // 3136
#define EW    147456           // per-expert W elems
#define BW_   147456           // per-sample Wmix elems: [cc4][tap9][co128][ci32]
#define XCOLS 66               // padded cols: input col = c-1 in [-1,64]
#define XROWS 58               // padded rows
#define XRST  (XCOLS*CIN)      // 8448
#define XBSZ  (XROWS*XRST)     // 489984

static __device__ __forceinline__ unsigned short f2bf(float f) {
    unsigned u = __builtin_bit_cast(unsigned, f);
    return (unsigned short)((u + 0x7FFFu + ((u >> 16) & 1u)) >> 16);
}

static __device__ __forceinline__ void gload16(const void* g, void* l) {
    __builtin_amdgcn_global_load_lds(
        (const __attribute__((address_space(1))) void*)g,
        (__attribute__((address_space(3))) void*)l, 16, 0, 0);
}

// ---------------------------------------------------------------------------
// prep: blocks [0,576) mix weights; [576,1504) cast/pad x. One launch.
// ---------------------------------------------------------------------------
__global__ __launch_bounds__(256) void prep_kernel(const float* __restrict__ W,
                                                   const float* __restrict__ r,
                                                   const float* __restrict__ x,
                                                   unsigned short* __restrict__ Wmix,
                                                   unsigned short* __restrict__ xbf) {
    __shared__ unsigned short tile[CIN * XCOLS];     // xcast branch only (16.9 KB)
    const int bid = blockIdx.x;
    const int t   = threadIdx.x;

    if (bid < 576) {
        // Wmix[b][cc][tap][co][ci_l] = sum_e r[b,e]*W[e][co][cc*32+ci_l][tap]
        int o = bid * 256 + t;                       // [0,147456)
        int ci_l = o & 31;
        int o2   = o >> 5;
        int co   = o2 & 127;
        int o3   = o2 >> 7;                          // [0,36)
        int tap  = o3 % 9;
        int cc   = o3 / 9;
        size_t src = ((size_t)co * CIN + cc*32 + ci_l) * 9 + tap;
        float w0 = W[src], w1 = W[src + EW], w2 = W[src + 2*EW], w3 = W[src + 3*EW];
        #pragma unroll
        for (int b = 0; b < 16; ++b) {
            float acc = r[b*4+0]*w0 + r[b*4+1]*w1 + r[b*4+2]*w2 + r[b*4+3]*w3;
            Wmix[(size_t)b * BW_ + o] = f2bf(acc);
        }
    } else {
        // xbf[b][row][col][ci], halo/right-pad zeroed, ci-fastest (LDS transpose)
        int bb  = bid - 576;                         // [0,928)
        int row = bb % XROWS;
        int b   = bb / XROWS;
        int hin = row - 1;
        const float* xb = x + (size_t)b * CIN * SP;
        for (int s = t; s < CIN * XCOLS; s += 256) {
            int col = s % XCOLS;
            int ci  = s / XCOLS;
            int w   = col - 1;
            unsigned short v = 0;
            if ((unsigned)hin < 56u && (unsigned)w < 56u)
                v = f2bf(xb[(size_t)ci * SP + hin*56 + w]);
            tile[ci * XCOLS + col] = v;
        }
        __syncthreads();
        unsigned short* dst = xbf + (size_t)b * XBSZ + (size_t)row * XRST;
        for (int s = t; s < XCOLS * 16; s += 256) {
            int oc  = s & 15;
            int col = s >> 4;
            s16x8 v;
            #pragma unroll
            for (int j = 0; j < 8; ++j) v[j] = (short)tile[(oc*8 + j) * XCOLS + col];
            *(s16x8*)&dst[col * CIN + oc*8] = v;
        }
    }
}

// ---------------------------------------------------------------------------
// conv: block=(b,h): C[128co][64px] += A[128][1152] * B[1152][64px].
// 4 waves = 2(co-half wm) x 2(px-half wn); wave = 64co x 32px (4mf x 2nf).
// 18 iters x BK=64. Per iter: issue 6 DMA for it+1; s_waitcnt vmcnt(6)
// (own oldest 6 = it's data; prefetch stays in flight); s_barrier;
// setprio(1) 12x ds_read_b128 + 32 MFMA setprio(0); s_barrier (buffer guard).
// LDS: 2 bufs x 24KB, XOR-swizzled both sides (rule #21).
// ---------------------------------------------------------------------------
__global__ __launch_bounds__(256, 3) void conv_mfma(const unsigned short* __restrict__ xbf,
                                                    const unsigned short* __restrict__ Wmix,
                                                    float* __restrict__ out) {
    __shared__ __align__(16) unsigned short lds[24576];   // 48 KB
    char* ldsb = (char*)lds;

    const int bid = blockIdx.x;
    const int bs  = (bid & 7) * 112 + (bid >> 3);    // bijective XCD swizzle (896=8*112)
    const int b   = bs / 56;
    const int h   = bs % 56;
    const int t    = threadIdx.x;
    const int lane = t & 63;
    const int wid  = t >> 6;
    const int wm   = wid >> 1;                       // co half
    const int wn   = wid & 1;                        // px half
    const int l15  = lane & 15;
    const int kg   = lane >> 4;

    const unsigned short* WmixB = Wmix + (size_t)b * BW_;
    const unsigned short* xbB   = xbf  + (size_t)b * XBSZ;

    // staging per-thread source swizzle: row=t>>2, slot=t&3, chunk = slot^((row>>1)&3)
    const int srow = t >> 2;
    const int ssl  = (t & 3) ^ ((srow >> 1) & 3);
    const int a_off = srow * 32 + ssl * 8;           // elems into a 4096-elem A slab
    // frag-read swizzle (per-lane constant): byte slot' for ci-chunk kg
    const int swz = (kg ^ ((l15 >> 1) & 3)) * 16;
    const int a_rd = (wm * 64 + l15) * 64 + swz;     // + mf*1024 + tp*8192 (+bufo)
    const int b_rd = 16384 + (wn * 32 + l15) * 64 + swz; // + nf*1024 + tp*4096 (+bufo)

    f32x4 acc[4][2];
    #pragma unroll
    for (int mf = 0; mf < 4; ++mf)
        #pragma unroll
        for (int nf = 0; nf < 2; ++nf) acc[mf][nf] = (f32x4)0.f;

    auto stage = [&](int it) {
        const int bufo = (it & 1) * 24576;           // bytes
        #pragma unroll
        for (int tp = 0; tp < 2; ++tp) {
            const int s   = it * 2 + tp;             // k-slab 0..35
            const int cc  = s / 9;
            const int tap = s % 9;
            const int kh  = tap / 3;
            const int kw  = tap % 3;
            // A slab: 8KB = 2 DMA rounds (512 x 16B), lds dest lane-linear
            const unsigned short* ga = WmixB + s * 4096 + a_off;
            char* la = ldsb + bufo + tp * 8192 + wid * 1024;
            gload16(ga,        la);
            gload16(ga + 2048, la + 4096);           // round 1: co += 64
            // B tile: 64px x 32ci = 4KB = 1 DMA round
            const unsigned short* gb = xbB + (size_t)(h + kh) * XRST
                                       + (srow + kw) * CIN + cc * 32 + ssl * 8;
            char* lb = ldsb + bufo + 16384 + tp * 4096 + wid * 1024;
            gload16(gb, lb);
        }
    };

    auto compute = [&](int it) {
        const int bufo = (it & 1) * 24576;
        #pragma unroll
        for (int tp = 0; tp < 2; ++tp) {
            s16x8 af[4], bf[2];
            #pragma unroll
            for (int mf = 0; mf < 4; ++mf)
                af[mf] = *(const s16x8*)(ldsb + bufo + tp*8192 + a_rd + mf*1024);
            #pragma unroll
            for (int nf = 0; nf < 2; ++nf)
                bf[nf] = *(const s16x8*)(ldsb + bufo + tp*4096 + b_rd + nf*1024);
            #pragma unroll
            for (int mf = 0; mf < 4; ++mf)
                #pragma unroll
                for (int nf = 0; nf < 2; ++nf)
                    acc[mf][nf] = __builtin_amdgcn_mfma_f32_16x16x32_bf16(
                        af[mf], bf[nf], acc[mf][nf], 0, 0, 0);
        }
    };

    stage(0);
    #pragma unroll
    for (int it = 0; it < 18; ++it) {
        if (it + 1 < 18) {
            stage(it + 1);                           // 6 DMAs for next iter
            // wait own oldest 6 (= iter it's data); leave 6 prefetch in flight
            asm volatile("s_waitcnt vmcnt(6)" ::: "memory");
        } else {
            asm volatile("s_waitcnt vmcnt(0)" ::: "memory");
        }
        __builtin_amdgcn_s_barrier();                // all waves' it-data landed
        __builtin_amdgcn_sched_barrier(0);           // pin: no hoist above barrier
        __builtin_amdgcn_s_setprio(1);
        compute(it);
        __builtin_amdgcn_s_setprio(0);
        __builtin_amdgcn_sched_barrier(0);
        __builtin_amdgcn_s_barrier();                // guard buf reuse by stage(it+2)
    }

    // store: D col(px)=l15, row(co)=kg*4+rg
    #pragma unroll
    for (int nf = 0; nf < 2; ++nf) {
        int wout = wn*32 + nf*16 + l15;
        if (wout < 56) {
            #pragma unroll
            for (int mf = 0; mf < 4; ++mf)
                #pragma unroll
                for (int rg = 0; rg < 4; ++rg) {
                    int co = wm*64 + mf*16 + kg*4 + rg;
                    out[(((size_t)b*COUT + co)*HH + h)*WW + wout] = acc[mf][nf][rg];
                }
        }
    }
}

extern "C" void kernel_launch(void* const* d_in, const int* in_sizes, int n_in,
                              void* d_out, int out_size, void* d_ws, size_t ws_size,
                              hipStream_t stream) {
    const float* x = (const float*)d_in[0];          // [16,128,56,56]
    const float* r = (const float*)d_in[1];          // [16,4]
    const float* W = (const float*)d_in[2];          // [4,128,128,3,3]
    float* outp = (float*)d_out;                     // [16,128,56,56]
    unsigned short* Wmix = (unsigned short*)d_ws;            // 4.72 MB
    unsigned short* xbf  = Wmix + (size_t)16 * BW_;          // 15.68 MB

    prep_kernel<<<1504, 256, 0, stream>>>(W, r, x, Wmix, xbf);
    conv_mfma  <<<896,  256, 0, stream>>>(xbf, Wmix, outp);
}

// Round 7
// 45.597 us; speedup vs baseline: 2.0916x; 1.0281x over previous
//
#include <hip/hip_runtime.h>

// CondConv2d B=16,CIN=COUT=128,H=W=56,E=4,3x3,pad=1 fp32.
// (1) prep: fold routing into bf16 Wmix[b][cc][tap][co][ci_l]  +  cast x into
//     padded bf16 xbf[b][row58][col66][ci128] (halo zeroed).
// (2) conv: per (b, h-pair) block a 128co x 128px x K=1152 MFMA GEMM on
//     mfma_f32_32x32x16_bf16 (64x64 wave tile = 32 FLOP/LDS-byte), BK=32,
//     double-buffered global_load_lds with counted vmcnt, XOR-swizzled LDS.

typedef float  f32x16 __attribute__((ext_vector_type(16)));
typedef short  s16x8  __attribute__((ext_vector_type(8)));

#define CIN   128
#define COUT  128
#define HH    56
#define WW    56
#define SP    (HH*WW)          // 3136
#define EW    147456           // per-expert W elems
#define BW_   147456           // per-sample Wmix elems: [cc4][tap9][co128][ci32]
#define XCOLS 66               // padded cols: input col = c-1 in [-1,64]
#define XROWS 58               // padded rows
#define XRST  (XCOLS*CIN)      // 8448
#define XBSZ  (XROWS*XRST)     // 489984

static __device__ __forceinline__ unsigned short f2bf(float f) {
    unsigned u = __builtin_bit_cast(unsigned, f);
    return (unsigned short)((u + 0x7FFFu + ((u >> 16) & 1u)) >> 16);
}

static __device__ __forceinline__ void gload16(const void* g, void* l) {
    __builtin_amdgcn_global_load_lds(
        (const __attribute__((address_space(1))) void*)g,
        (__attribute__((address_space(3))) void*)l, 16, 0, 0);
}

// ---------------------------------------------------------------------------
// prep: blocks [0,576) mix weights; [576,1504) cast/pad x. One launch.
// ---------------------------------------------------------------------------
__global__ __launch_bounds__(256) void prep_kernel(const float* __restrict__ W,
                                                   const float* __restrict__ r,
                                                   const float* __restrict__ x,
                                                   unsigned short* __restrict__ Wmix,
                                                   unsigned short* __restrict__ xbf) {
    __shared__ unsigned short tile[CIN * XCOLS];     // xcast branch only (16.9 KB)
    const int bid = blockIdx.x;
    const int t   = threadIdx.x;

    if (bid < 576) {
        // Wmix[b][cc][tap][co][ci_l] = sum_e r[b,e]*W[e][co][cc*32+ci_l][tap]
        int o = bid * 256 + t;                       // [0,147456)
        int ci_l = o & 31;
        int o2   = o >> 5;
        int co   = o2 & 127;
        int o3   = o2 >> 7;                          // [0,36)
        int tap  = o3 % 9;
        int cc   = o3 / 9;
        size_t src = ((size_t)co * CIN + cc*32 + ci_l) * 9 + tap;
        float w0 = W[src], w1 = W[src + EW], w2 = W[src + 2*EW], w3 = W[src + 3*EW];
        #pragma unroll
        for (int b = 0; b < 16; ++b) {
            float acc = r[b*4+0]*w0 + r[b*4+1]*w1 + r[b*4+2]*w2 + r[b*4+3]*w3;
            Wmix[(size_t)b * BW_ + o] = f2bf(acc);
        }
    } else {
        // xbf[b][row][col][ci], halo/right-pad zeroed, ci-fastest (LDS transpose)
        int bb  = bid - 576;                         // [0,928)
        int row = bb % XROWS;
        int b   = bb / XROWS;
        int hin = row - 1;
        const float* xb = x + (size_t)b * CIN * SP;
        for (int s = t; s < CIN * XCOLS; s += 256) {
            int col = s % XCOLS;
            int ci  = s / XCOLS;
            int w   = col - 1;
            unsigned short v = 0;
            if ((unsigned)hin < 56u && (unsigned)w < 56u)
                v = f2bf(xb[(size_t)ci * SP + hin*56 + w]);
            tile[ci * XCOLS + col] = v;
        }
        __syncthreads();
        unsigned short* dst = xbf + (size_t)b * XBSZ + (size_t)row * XRST;
        for (int s = t; s < XCOLS * 16; s += 256) {
            int oc  = s & 15;
            int col = s >> 4;
            s16x8 v;
            #pragma unroll
            for (int j = 0; j < 8; ++j) v[j] = (short)tile[(oc*8 + j) * XCOLS + col];
            *(s16x8*)&dst[col * CIN + oc*8] = v;
        }
    }
}

// ---------------------------------------------------------------------------
// conv: block = (b, h-pair ph). C[128co][128px] (px = 2 rows x 64 padded cols).
// 4 waves = 2(co-half wm) x 2(row wn); wave = 64co x 64px via 32x32x16 MFMA
// (2mf x 2nf x 2ksub = 8 mfma / 8 ds_read_b128 per BK=32 iter). 36 iters.
// LDS buf 16KB = A slab [co128][ci32] + B slab [px128][ci32]; dbuf 32KB.
// Swizzle: 16B-slot' = slot ^ ((row>>1)&3)  (inverse on DMA src, fwd on read).
// Loop: stage(it+1) -> vmcnt(4) -> barrier -> setprio/MFMA -> barrier.
// ---------------------------------------------------------------------------
__global__ __launch_bounds__(256, 4) void conv_mfma(const unsigned short* __restrict__ xbf,
                                                    const unsigned short* __restrict__ Wmix,
                                                    float* __restrict__ out) {
    __shared__ __align__(16) char ldsb[32768];

    const int bid = blockIdx.x;
    const int bs  = (bid & 7) * 56 + (bid >> 3);     // bijective XCD swizzle (448=8*56)
    const int b   = bs / 28;
    const int ph  = bs % 28;                         // h-pair: rows {2ph, 2ph+1}
    const int t    = threadIdx.x;
    const int lane = t & 63;
    const int wid  = t >> 6;
    const int wm   = wid >> 1;                       // co half
    const int wn   = wid & 1;                        // row within pair / px half
    const int l31  = lane & 31;
    const int khalf= lane >> 5;
    const int swz  = (l31 >> 1) & 3;                 // read-side XOR

    const unsigned short* WmixB = Wmix + (size_t)b * BW_;
    const unsigned short* xbB   = xbf  + (size_t)b * XBSZ;

    // DMA source decomposition: round r covers rows r*64+(t>>2), 16B-slot (t&3).
    // Inverse swizzle on source so linear LDS dest holds swizzled data.
    const int arow = t >> 2;                         // 0..63
    const int ssl  = (t & 3) ^ ((t >> 3) & 3);       // source slot (both rounds)

    f32x16 acc[2][2];
    #pragma unroll
    for (int mf = 0; mf < 2; ++mf)
        #pragma unroll
        for (int nf = 0; nf < 2; ++nf) acc[mf][nf] = (f32x16)0.f;

    auto stage = [&](int it) {
        char* bufo = ldsb + (it & 1) * 16384;
        const int cc  = it / 9;
        const int tap = it % 9;
        const int kh  = tap / 3;
        const int kw  = tap % 3;
        // A slab: Wmix[s][co][ci_l] 8KB, rows 0-63 then 64-127
        const unsigned short* ga = WmixB + it * 4096 + arow * 32 + ssl * 8;
        gload16(ga,        bufo + wid * 1024);
        gload16(ga + 2048, bufo + 4096 + wid * 1024);
        // B slab: x rows {2ph, 2ph+1}+kh, cols (t>>2)+kw, ci chunk cc
        const unsigned short* gb = xbB + (size_t)(2*ph + kh) * XRST
                                   + (arow + kw) * CIN + cc * 32 + ssl * 8;
        gload16(gb,        bufo + 8192 + wid * 1024);
        gload16(gb + XRST, bufo + 8192 + 4096 + wid * 1024);
    };

    auto compute = [&](int it) {
        const char* Ab = ldsb + (it & 1) * 16384;
        const char* Bb = Ab + 8192;
        #pragma unroll
        for (int ksub = 0; ksub < 2; ++ksub) {
            const int slot16 = ((ksub * 2 + khalf) ^ swz) * 16;
            s16x8 af[2], bv[2];
            #pragma unroll
            for (int mf = 0; mf < 2; ++mf)
                af[mf] = *(const s16x8*)(Ab + wm*4096 + mf*2048 + l31*64 + slot16);
            #pragma unroll
            for (int nf = 0; nf < 2; ++nf)
                bv[nf] = *(const s16x8*)(Bb + wn*4096 + nf*2048 + l31*64 + slot16);
            #pragma unroll
            for (int mf = 0; mf < 2; ++mf)
                #pragma unroll
                for (int nf = 0; nf < 2; ++nf)
                    acc[mf][nf] = __builtin_amdgcn_mfma_f32_32x32x16_bf16(
                        af[mf], bv[nf], acc[mf][nf], 0, 0, 0);
        }
    };

    stage(0);
    #pragma unroll
    for (int it = 0; it < 36; ++it) {
        if (it + 1 < 36) {
            stage(it + 1);                           // 4 DMAs for next iter
            asm volatile("s_waitcnt vmcnt(4)" ::: "memory");  // own data landed
        } else {
            asm volatile("s_waitcnt vmcnt(0)" ::: "memory");
        }
        __builtin_amdgcn_s_barrier();
        __builtin_amdgcn_sched_barrier(0);
        __builtin_amdgcn_s_setprio(1);
        compute(it);
        __builtin_amdgcn_s_setprio(0);
        __builtin_amdgcn_sched_barrier(0);
        __builtin_amdgcn_s_barrier();                // guard buf reuse
    }

    // store: D col(px)=l31, row(co) = (reg&3) + 8*(reg>>2) + 4*khalf
    #pragma unroll
    for (int nf = 0; nf < 2; ++nf) {
        const int w = nf * 32 + l31;
        if (w < 56) {
            const int hrow = 2 * ph + wn;
            #pragma unroll
            for (int mf = 0; mf < 2; ++mf) {
                #pragma unroll
                for (int rg = 0; rg < 16; ++rg) {
                    int co = wm*64 + mf*32 + (rg & 3) + 8*(rg >> 2) + 4*khalf;
                    out[(((size_t)b*COUT + co)*HH + hrow)*WW + w] = acc[mf][nf][rg];
                }
            }
        }
    }
}

extern "C" void kernel_launch(void* const* d_in, const int* in_sizes, int n_in,
                              void* d_out, int out_size, void* d_ws, size_t ws_size,
                              hipStream_t stream) {
    const float* x = (const float*)d_in[0];          // [16,128,56,56]
    const float* r = (const float*)d_in[1];          // [16,4]
    const float* W = (const float*)d_in[2];          // [4,128,128,3,3]
    float* outp = (float*)d_out;                     // [16,128,56,56]
    unsigned short* Wmix = (unsigned short*)d_ws;            // 4.72 MB
    unsigned short* xbf  = Wmix + (size_t)16 * BW_;          // 15.68 MB

    prep_kernel<<<1504, 256, 0, stream>>>(W, r, x, Wmix, xbf);
    conv_mfma  <<<448,  256, 0, stream>>>(xbf, Wmix, outp);
}

// Round 8
// 44.873 us; speedup vs baseline: 2.1253x; 1.0161x over previous
//
#include <hip/hip_runtime.h>

// CondConv2d B=16,CIN=COUT=128,H=W=56,E=4,3x3,pad=1 fp32.
// (1) prep: fold routing into bf16 Wmix[b][cc][tap][co][ci_l]  +  cast x into
//     padded bf16 xbf[b][row58][col66][ci128] (halo zeroed).
// (2) conv: per (b, h-pair) block a 128co x 128px x K=1152 MFMA GEMM on
//     mfma_f32_32x32x16_bf16, BK=32, 36 iters. Depth-2 counted-vmcnt pipeline:
//     4 LDS buffers, stage(it+2) each iter, vmcnt(8), ONE barrier per iter.

typedef float  f32x16 __attribute__((ext_vector_type(16)));
typedef short  s16x8  __attribute__((ext_vector_type(8)));

#define CIN   128
#define COUT  128
#define HH    56
#define WW    56
#define SP    (HH*WW)          // 3136
#define EW    147456           // per-expert W elems
#define BW_   147456           // per-sample Wmix elems: [cc4][tap9][co128][ci32]
#define XCOLS 66               // padded cols: input col = c-1 in [-1,64]
#define XROWS 58               // padded rows
#define XRST  (XCOLS*CIN)      // 8448
#define XBSZ  (XROWS*XRST)     // 489984

static __device__ __forceinline__ unsigned short f2bf(float f) {
    unsigned u = __builtin_bit_cast(unsigned, f);
    return (unsigned short)((u + 0x7FFFu + ((u >> 16) & 1u)) >> 16);
}

static __device__ __forceinline__ void gload16(const void* g, void* l) {
    __builtin_amdgcn_global_load_lds(
        (const __attribute__((address_space(1))) void*)g,
        (__attribute__((address_space(3))) void*)l, 16, 0, 0);
}

// ---------------------------------------------------------------------------
// prep: blocks [0,576) mix weights; [576,1504) cast/pad x. One launch.
// ---------------------------------------------------------------------------
__global__ __launch_bounds__(256) void prep_kernel(const float* __restrict__ W,
                                                   const float* __restrict__ r,
                                                   const float* __restrict__ x,
                                                   unsigned short* __restrict__ Wmix,
                                                   unsigned short* __restrict__ xbf) {
    __shared__ unsigned short tile[CIN * XCOLS];     // xcast branch only (16.9 KB)
    const int bid = blockIdx.x;
    const int t   = threadIdx.x;

    if (bid < 576) {
        // Wmix[b][cc][tap][co][ci_l] = sum_e r[b,e]*W[e][co][cc*32+ci_l][tap]
        int o = bid * 256 + t;                       // [0,147456)
        int ci_l = o & 31;
        int o2   = o >> 5;
        int co   = o2 & 127;
        int o3   = o2 >> 7;                          // [0,36)
        int tap  = o3 % 9;
        int cc   = o3 / 9;
        size_t src = ((size_t)co * CIN + cc*32 + ci_l) * 9 + tap;
        float w0 = W[src], w1 = W[src + EW], w2 = W[src + 2*EW], w3 = W[src + 3*EW];
        #pragma unroll
        for (int b = 0; b < 16; ++b) {
            float acc = r[b*4+0]*w0 + r[b*4+1]*w1 + r[b*4+2]*w2 + r[b*4+3]*w3;
            Wmix[(size_t)b * BW_ + o] = f2bf(acc);
        }
    } else {
        // xbf[b][row][col][ci], halo/right-pad zeroed, ci-fastest (LDS transpose)
        int bb  = bid - 576;                         // [0,928)
        int row = bb % XROWS;
        int b   = bb / XROWS;
        int hin = row - 1;
        const float* xb = x + (size_t)b * CIN * SP;
        for (int s = t; s < CIN * XCOLS; s += 256) {
            int col = s % XCOLS;
            int ci  = s / XCOLS;
            int w   = col - 1;
            unsigned short v = 0;
            if ((unsigned)hin < 56u && (unsigned)w < 56u)
                v = f2bf(xb[(size_t)ci * SP + hin*56 + w]);
            tile[ci * XCOLS + col] = v;
        }
        __syncthreads();
        unsigned short* dst = xbf + (size_t)b * XBSZ + (size_t)row * XRST;
        for (int s = t; s < XCOLS * 16; s += 256) {
            int oc  = s & 15;
            int col = s >> 4;
            s16x8 v;
            #pragma unroll
            for (int j = 0; j < 8; ++j) v[j] = (short)tile[(oc*8 + j) * XCOLS + col];
            *(s16x8*)&dst[col * CIN + oc*8] = v;
        }
    }
}

// ---------------------------------------------------------------------------
// conv: block = (b, h-pair ph). C[128co][128px] (px = 2 rows x 64 padded cols).
// 4 waves = 2(co-half wm) x 2(row wn); wave = 64co x 64px via 32x32x16 MFMA
// (2mf x 2nf x 2ksub = 8 mfma / 8 ds_read_b128 per BK=32 iter). 36 iters.
// Pipeline: 4 bufs x 16KB (A 8KB + B 8KB); iter it: stage(it+2) -> vmcnt(8)
// (2 iters / 8 DMAs stay in flight) -> barrier -> setprio/MFMA. One barrier:
// window(it) has compute(it)<-buf[it&3], DMA lands buf[(it+2)&3], stage(it+3)
// ->buf[(it+3)&3] — all distinct mod 4.
// Swizzle: 16B-slot' = slot ^ ((row>>1)&3)  (inverse on DMA src, fwd on read).
// ---------------------------------------------------------------------------
__global__ __launch_bounds__(256, 2) void conv_mfma(const unsigned short* __restrict__ xbf,
                                                    const unsigned short* __restrict__ Wmix,
                                                    float* __restrict__ out) {
    __shared__ __align__(16) char ldsb[65536];

    const int bid = blockIdx.x;
    const int bs  = (bid & 7) * 56 + (bid >> 3);     // bijective XCD swizzle (448=8*56)
    const int b   = bs / 28;
    const int ph  = bs % 28;                         // h-pair: rows {2ph, 2ph+1}
    const int t    = threadIdx.x;
    const int lane = t & 63;
    const int wid  = t >> 6;
    const int wm   = wid >> 1;                       // co half
    const int wn   = wid & 1;                        // row within pair
    const int l31  = lane & 31;
    const int khalf= lane >> 5;
    const int swz  = (l31 >> 1) & 3;                 // read-side XOR

    const unsigned short* WmixB = Wmix + (size_t)b * BW_;
    const unsigned short* xbB   = xbf  + (size_t)b * XBSZ;

    // DMA source decomposition: row (t>>2), 16B-slot (t&3), inverse-swizzled
    const int arow = t >> 2;                         // 0..63
    const int ssl  = (t & 3) ^ ((t >> 3) & 3);       // source slot (both rounds)

    f32x16 acc[2][2];
    #pragma unroll
    for (int mf = 0; mf < 2; ++mf)
        #pragma unroll
        for (int nf = 0; nf < 2; ++nf) acc[mf][nf] = (f32x16)0.f;

    auto stage = [&](int it) {
        char* bufo = ldsb + (it & 3) * 16384;
        const int cc  = it / 9;
        const int tap = it % 9;
        const int kh  = tap / 3;
        const int kw  = tap % 3;
        // A slab: Wmix[it][co][ci_l] 8KB, rows 0-63 then 64-127
        const unsigned short* ga = WmixB + it * 4096 + arow * 32 + ssl * 8;
        gload16(ga,        bufo + wid * 1024);
        gload16(ga + 2048, bufo + 4096 + wid * 1024);
        // B slab: x rows {2ph,2ph+1}+kh, col (t>>2)+kw, ci chunk cc
        const unsigned short* gb = xbB + (size_t)(2*ph + kh) * XRST
                                   + (arow + kw) * CIN + cc * 32 + ssl * 8;
        gload16(gb,        bufo + 8192 + wid * 1024);
        gload16(gb + XRST, bufo + 8192 + 4096 + wid * 1024);
    };

    auto compute = [&](int it) {
        const char* Ab = ldsb + (it & 3) * 16384;
        const char* Bb = Ab + 8192;
        #pragma unroll
        for (int ksub = 0; ksub < 2; ++ksub) {
            const int slot16 = ((ksub * 2 + khalf) ^ swz) * 16;
            s16x8 af[2], bv[2];
            #pragma unroll
            for (int mf = 0; mf < 2; ++mf)
                af[mf] = *(const s16x8*)(Ab + wm*4096 + mf*2048 + l31*64 + slot16);
            #pragma unroll
            for (int nf = 0; nf < 2; ++nf)
                bv[nf] = *(const s16x8*)(Bb + wn*4096 + nf*2048 + l31*64 + slot16);
            #pragma unroll
            for (int mf = 0; mf < 2; ++mf)
                #pragma unroll
                for (int nf = 0; nf < 2; ++nf)
                    acc[mf][nf] = __builtin_amdgcn_mfma_f32_32x32x16_bf16(
                        af[mf], bv[nf], acc[mf][nf], 0, 0, 0);
        }
    };

    stage(0);
    stage(1);
    #pragma unroll
    for (int it = 0; it < 36; ++it) {
        if (it + 2 < 36) {
            stage(it + 2);                           // 4 DMAs, two iters ahead
            asm volatile("s_waitcnt vmcnt(8)" ::: "memory");   // iter it landed
        } else if (it + 1 < 36) {
            asm volatile("s_waitcnt vmcnt(4)" ::: "memory");
        } else {
            asm volatile("s_waitcnt vmcnt(0)" ::: "memory");
        }
        __builtin_amdgcn_s_barrier();                // all waves' it-data visible
        __builtin_amdgcn_sched_barrier(0);           // pin: nothing crosses
        __builtin_amdgcn_s_setprio(1);
        compute(it);
        __builtin_amdgcn_s_setprio(0);
        __builtin_amdgcn_sched_barrier(0);
    }

    // store: D col(px)=l31, row(co) = (reg&3) + 8*(reg>>2) + 4*khalf
    #pragma unroll
    for (int nf = 0; nf < 2; ++nf) {
        const int w = nf * 32 + l31;
        if (w < 56) {
            const int hrow = 2 * ph + wn;
            #pragma unroll
            for (int mf = 0; mf < 2; ++mf) {
                #pragma unroll
                for (int rg = 0; rg < 16; ++rg) {
                    int co = wm*64 + mf*32 + (rg & 3) + 8*(rg >> 2) + 4*khalf;
                    out[(((size_t)b*COUT + co)*HH + hrow)*WW + w] = acc[mf][nf][rg];
                }
            }
        }
    }
}

extern "C" void kernel_launch(void* const* d_in, const int* in_sizes, int n_in,
                              void* d_out, int out_size, void* d_ws, size_t ws_size,
                              hipStream_t stream) {
    const float* x = (const float*)d_in[0];          // [16,128,56,56]
    const float* r = (const float*)d_in[1];          // [16,4]
    const float* W = (const float*)d_in[2];          // [4,128,128,3,3]
    float* outp = (float*)d_out;                     // [16,128,56,56]
    unsigned short* Wmix = (unsigned short*)d_ws;            // 4.72 MB
    unsigned short* xbf  = Wmix + (size_t)16 * BW_;          // 15.68 MB

    prep_kernel<<<1504, 256, 0, stream>>>(W, r, x, Wmix, xbf);
    conv_mfma  <<<448,  256, 0, stream>>>(xbf, Wmix, outp);
}

// Round 9
// 36.807 us; speedup vs baseline: 2.5910x; 1.2191x over previous
//
#include <hip/hip_runtime.h>

// CondConv2d B=16,CIN=COUT=128,H=W=56,E=4,3x3,pad=1 fp32.
// (1) mix: fold routing into bf16 Wmix[b][cc][tap][co][ci_l] (conv linear in W).
// (2) conv: block=(b,h-pair): 128co x 128px x K=1152 GEMM on mfma_32x32x16_bf16.
//     A: DMA (global_load_lds) 4-deep pipeline, counted vmcnt, 1 barrier/window.
//     B: x staged fp32->bf16 in-kernel ONCE per ci-chunk (no xcast pass),
//        swizzled ds_write + swizzled ds_read (both-sides, rule #21).

typedef float  f32x16 __attribute__((ext_vector_type(16)));
typedef short  s16x8  __attribute__((ext_vector_type(8)));
typedef unsigned short u16;

#define CIN   128
#define COUT  128
#define HH    56
#define WW    56
#define SP    (HH*WW)          // 3136
#define EW    147456           // per-expert W elems
#define BW_   147456           // per-sample Wmix elems: [cc4][tap9][co128][ci32]
#define XB    16896            // xbuf bytes: 4 rows x 66 cols x 64 B (32 ci bf16)
#define AB    8192             // one A slab: 128 co x 32 ci bf16

static __device__ __forceinline__ u16 f2bf(float f) {
    unsigned u = __builtin_bit_cast(unsigned, f);
    return (u16)((u + 0x7FFFu + ((u >> 16) & 1u)) >> 16);
}

static __device__ __forceinline__ void gload16(const void* g, void* l) {
    __builtin_amdgcn_global_load_lds(
        (const __attribute__((address_space(1))) void*)g,
        (__attribute__((address_space(3))) void*)l, 16, 0, 0);
}

// ---------------------------------------------------------------------------
// mix: Wmix[b][cc][tap][co][ci_l] = sum_e r[b,e]*W[e][co][cc*32+ci_l][tap]
// Each thread reads its 4 expert weights once, writes all 16 samples.
// ---------------------------------------------------------------------------
__global__ __launch_bounds__(256) void mix_kernel(const float* __restrict__ W,
                                                  const float* __restrict__ r,
                                                  u16* __restrict__ Wmix) {
    int o = blockIdx.x * 256 + threadIdx.x;      // [0, 147456)
    int ci_l = o & 31;
    int o2   = o >> 5;
    int co   = o2 & 127;
    int o3   = o2 >> 7;                          // [0,36)
    int tap  = o3 % 9;
    int cc   = o3 / 9;
    size_t src = ((size_t)co * CIN + cc*32 + ci_l) * 9 + tap;
    float w0 = W[src], w1 = W[src + EW], w2 = W[src + 2*EW], w3 = W[src + 3*EW];
    #pragma unroll
    for (int b = 0; b < 16; ++b) {
        float acc = r[b*4+0]*w0 + r[b*4+1]*w1 + r[b*4+2]*w2 + r[b*4+3]*w3;
        Wmix[(size_t)b * BW_ + o] = f2bf(acc);
    }
}

// ---------------------------------------------------------------------------
// conv: block=(b, h-pair ph). 4 waves = 2(co wm) x 2(row wn); wave 64co x 64px.
// 36 windows (cc,tap): [stage A(it+2) DMA; vmcnt(4); barrier; 8 ds_read+8 MFMA].
// xbuf[4][66][32ci] bf16 restaged per cc (4x) from fp32 x behind one barrier.
// Swizzle (both A and B): 16B-slot' = slot ^ ((row_or_col>>1)&3).
// LDS: xbuf 16.9KB + 4 A bufs 32KB = 49.7KB -> 3 blocks/CU.
// ---------------------------------------------------------------------------
__global__ __launch_bounds__(256, 3) void conv_mfma(const float* __restrict__ x,
                                                    const u16* __restrict__ Wmix,
                                                    float* __restrict__ out) {
    __shared__ __align__(16) char ldsb[XB + 4*AB];

    const int bid = blockIdx.x;
    const int bs  = (bid & 7) * 56 + (bid >> 3);     // bijective XCD swizzle (448=8*56)
    const int b   = bs / 28;
    const int ph  = bs % 28;                         // rows {2ph, 2ph+1}
    const int t    = threadIdx.x;
    const int lane = t & 63;
    const int wid  = t >> 6;
    const int wm   = wid >> 1;                       // co half
    const int wn   = wid & 1;                        // output row within pair
    const int l31  = lane & 31;
    const int khalf= lane >> 5;

    const u16*   WmixB = Wmix + (size_t)b * BW_;
    const float* xbB   = x + (size_t)b * CIN * SP;

    // A DMA source decomposition (inverse-swizzled so linear LDS dest is swizzled)
    const int arow = t >> 2;                          // co 0..63 (round0), +64 (round1)
    const int ssl  = (t & 3) ^ ((t >> 3) & 3);        // source 16B-slot

    f32x16 acc[2][2];
    #pragma unroll
    for (int mf = 0; mf < 2; ++mf)
        #pragma unroll
        for (int nf = 0; nf < 2; ++nf) acc[mf][nf] = (f32x16)0.f;

    auto stageA = [&](int it) {
        char* bufo = ldsb + XB + (it & 3) * AB;
        const u16* ga = WmixB + it * 4096 + arow * 32 + ssl * 8;
        gload16(ga,        bufo + wid * 1024);        // co 0..63
        gload16(ga + 2048, bufo + 4096 + wid * 1024); // co 64..127
    };

    // stage x chunk cc into xbuf: [row 0..3][col 1..64][ci 32], swizzled writes.
    auto stageX = [&](int cc) {
        #pragma unroll
        for (int i = 0; i < 4; ++i) {
            int slot = i * 256 + t;                  // 1024 slots
            int c    = 1 + (slot & 63);              // col 1..64 (w = c-1)
            int row  = (slot >> 6) & 3;              // 0..3
            int g    = slot >> 8;                    // ci group 0..3
            int rr   = 2*ph - 1 + row;               // input row
            int w    = c - 1;
            const float* p = xbB + (size_t)(cc*32 + g*8) * SP + rr*56 + w;
            bool rowok = (unsigned)rr < 56u;
            bool colok = w < 56;
            s16x8 v;
            #pragma unroll
            for (int j = 0; j < 8; ++j) {
                float f = (rowok && colok) ? p[j * SP] : 0.f;
                v[j] = (short)f2bf(f);
            }
            int so = ((row*66 + c)*64) + ((g ^ ((c >> 1) & 3)) * 16);
            *(s16x8*)(ldsb + so) = v;
        }
    };

    auto compute = [&](int it, int kh, int kw) {
        const char* Ab = ldsb + XB + (it & 3) * AB;
        #pragma unroll
        for (int ksub = 0; ksub < 2; ++ksub) {
            const int s = ksub * 2 + khalf;
            s16x8 af[2], bv[2];
            #pragma unroll
            for (int mf = 0; mf < 2; ++mf)
                af[mf] = *(const s16x8*)(Ab + (wm*64 + mf*32 + l31)*64
                                            + ((s ^ ((l31 >> 1) & 3)) * 16));
            #pragma unroll
            for (int nf = 0; nf < 2; ++nf) {
                const int c = l31 + nf*32 + kw;      // 0..65
                bv[nf] = *(const s16x8*)(ldsb + ((wn + kh)*66 + c)*64
                                              + ((s ^ ((c >> 1) & 3)) * 16));
            }
            #pragma unroll
            for (int mf = 0; mf < 2; ++mf)
                #pragma unroll
                for (int nf = 0; nf < 2; ++nf)
                    acc[mf][nf] = __builtin_amdgcn_mfma_f32_32x32x16_bf16(
                        af[mf], bv[nf], acc[mf][nf], 0, 0, 0);
        }
    };

    // --- prologue: halo cols (c=0,65) zero once; x chunk 0; A slabs 0,1 ---
    if (t < 32) {
        int row = t >> 3, ch = ((t >> 2) & 1) ? 65 : 0, sl = t & 3;
        *(s16x8*)(ldsb + (row*66 + ch)*64 + sl*16) = (s16x8)0;
    }
    stageX(0);
    stageA(0);
    stageA(1);
    asm volatile("s_waitcnt lgkmcnt(0)" ::: "memory");

    #pragma unroll
    for (int cc = 0; cc < 4; ++cc) {
        if (cc) {
            __builtin_amdgcn_s_barrier();            // all waves done reading xbuf
            stageX(cc);                              // compiler waits its own loads,
            asm volatile("s_waitcnt lgkmcnt(0)" ::: "memory");  // DMAs stay in flight
            __builtin_amdgcn_sched_barrier(0);
        }
        #pragma unroll
        for (int tap = 0; tap < 9; ++tap) {
            const int it = cc * 9 + tap;
            if (it + 2 < 36) {
                stageA(it + 2);
                asm volatile("s_waitcnt vmcnt(4)" ::: "memory");  // it's slab landed
            } else if (it + 1 < 36) {
                asm volatile("s_waitcnt vmcnt(2)" ::: "memory");
            } else {
                asm volatile("s_waitcnt vmcnt(0)" ::: "memory");
            }
            __builtin_amdgcn_s_barrier();
            __builtin_amdgcn_sched_barrier(0);
            __builtin_amdgcn_s_setprio(1);
            compute(it, tap / 3, tap % 3);
            __builtin_amdgcn_s_setprio(0);
            __builtin_amdgcn_sched_barrier(0);
        }
    }

    // store: D col(px)=l31, row(co) = (reg&3) + 8*(reg>>2) + 4*khalf
    #pragma unroll
    for (int nf = 0; nf < 2; ++nf) {
        const int w = nf * 32 + l31;
        if (w < 56) {
            const int hrow = 2 * ph + wn;
            #pragma unroll
            for (int mf = 0; mf < 2; ++mf) {
                #pragma unroll
                for (int rg = 0; rg < 16; ++rg) {
                    int co = wm*64 + mf*32 + (rg & 3) + 8*(rg >> 2) + 4*khalf;
                    out[(((size_t)b*COUT + co)*HH + hrow)*WW + w] = acc[mf][nf][rg];
                }
            }
        }
    }
}

extern "C" void kernel_launch(void* const* d_in, const int* in_sizes, int n_in,
                              void* d_out, int out_size, void* d_ws, size_t ws_size,
                              hipStream_t stream) {
    const float* x = (const float*)d_in[0];          // [16,128,56,56]
    const float* r = (const float*)d_in[1];          // [16,4]
    const float* W = (const float*)d_in[2];          // [4,128,128,3,3]
    float* outp = (float*)d_out;                     // [16,128,56,56]
    u16* Wmix = (u16*)d_ws;                          // 4.72 MB

    mix_kernel<<<576, 256, 0, stream>>>(W, r, Wmix);
    conv_mfma <<<448, 256, 0, stream>>>(x, Wmix, outp);
}